// Round 17
// baseline (109.900 us; speedup 1.0000x reference)
//
#include <hip/hip_runtime.h>
#include <math.h>

#define B_SZ   4
#define N_PTS  2048
#define EPSF   1e-6f
#define CAP    240     // candidate-list capacity per (wave,target); LDS <= 32 KB -> 5 blocks/CU

// ---- workspace float-index layout ----
#define WS_KNN_R 0                       // 4*6144 real knn dists
#define WS_KNN_F 24576                   // 4*6144 fake knn dists
#define WS_FEAS  49152                   // 512 feasibility partials
#define WS_PSIP  49664                   // 512 psi partials
#define WS_RSUM  50176                   // 4 per-batch sum|r|
#define WS_Q     50180                   // 58 quantile outputs
#define WS_TICK  50240                   // uint ticket (zeroed by pair blk 0)
#define QZF (WS_Q + 0)
#define QZR (WS_Q + 7)
#define QXF (WS_Q + 14)
#define QXR (WS_Q + 19)
#define QYF (WS_Q + 24)
#define QYR (WS_Q + 29)
#define QDR (WS_Q + 34)   // 4 batches x 3 (real knn)
#define QDF (WS_Q + 46)   // 4 batches x 3 (fake knn)
#define COMP_SCALE 128.0f     // 2048 bins over [-8,8), width 1/128
#define KNN_SCALE  512.0f     // 2048 bins over [0,4),  width 1/512

__constant__ float c_qs7[7] = {0.05f, 0.1f, 0.25f, 0.5f, 0.75f, 0.9f, 0.95f};
__constant__ float c_qs5[5] = {0.05f, 0.25f, 0.5f, 0.75f, 0.95f};
__constant__ float c_qs3[3] = {0.05f, 0.5f, 0.95f};

#define CE(a, b) { float _lo = fminf(a, b), _hi = fmaxf(a, b); a = _lo; b = _hi; }
#define RSQRT(x) __builtin_amdgcn_sqrtf(x)

__device__ __forceinline__ int clamp_bin(int b) {
    return (b < 0) ? 0 : (b > 2047 ? 2047 : b);
}

__device__ __forceinline__ void ins3a(float m[3], float v) {
    float h0 = fmaxf(m[0], v); m[0] = fminf(m[0], v);
    float h1 = fmaxf(m[1], h0); m[1] = fminf(m[1], h0);
    m[2] = fminf(m[2], h1);
}
__device__ __forceinline__ void ins5a(float m[5], float v) {
    float h0 = fmaxf(m[0], v); m[0] = fminf(m[0], v);
    float h1 = fmaxf(m[1], h0); m[1] = fminf(m[1], h0);
    float h2 = fmaxf(m[2], h1); m[2] = fminf(m[2], h1);
    float h3 = fmaxf(m[3], h2); m[3] = fminf(m[3], h2);
    m[4] = fminf(m[4], h3);
}

// kernel A shared-memory union: pair phase vs component-histogram phase
// p: 16384 + 8192 + 7680 = 32256 B; hist: 2 replicas x 2048 = 16384 B
union SmemA {
    struct {
        float2 sxy[N_PTS];                 // 16 KB
        float  sr[N_PTS];                  // 8 KB
        unsigned short slist[4 * 4 * CAP]; // 7.5 KB
    } p;
    unsigned int hist[2][2048];            // 16 KB (2 replicas; [0] reused as cum)
};

// ---------------- kernel A: pair work + component quantiles ----------------
// blocks 0..5     : component-array histogram quantiles (independent, LDS-local)
// blocks 6..517   : fake clouds — knn + feasibility + hexatic (4 pts/wave)
// blocks 518..1029: real clouds — knn only (4 pts/wave)
__global__ __launch_bounds__(256) void hs_pair_kernel(const float* __restrict__ real,
                                                      const float* __restrict__ fake,
                                                      float* __restrict__ ws) {
    __shared__ SmemA sm;
    __shared__ float s4[4];
    __shared__ unsigned int su4[4];
    const int tid = threadIdx.x, wave = tid >> 6, lane = tid & 63;
    const int blk = blockIdx.x;
    if (blk == 0 && tid == 0) ((unsigned int*)ws)[WS_TICK] = 0u;

    if (blk < 6) {
        // ---------- component histogram quantiles (LDS-local, 2 replicas) ----------
        const int aid = blk;               // 0 fakeZ,1 realZ,2 fakeX,3 realX,4 fakeY,5 realY
        const float* src = ((aid & 1) ? real : fake) + ((aid < 2) ? 2 : ((aid < 4) ? 0 : 1));
        const int nq = (aid < 2) ? 7 : 5;
        const int slot = (aid < 2) ? (QZF + aid * 7) : (QXF + (aid - 2) * 5);
        const float* qs = (aid < 2) ? c_qs7 : c_qs5;

        unsigned int* hflat = &sm.hist[0][0];
        for (int i = 0; i < 16; ++i) hflat[i * 256 + tid] = 0u;
        __syncthreads();
        const int rep = wave & 1;
        for (int u = 0; u < 32; ++u) {
            const float v = src[(size_t)(u * 256 + tid) * 3];
            const int bin = clamp_bin((int)floorf((v + 8.0f) * COMP_SCALE));
            atomicAdd(&sm.hist[rep][bin], 1u);
        }
        __syncthreads();
        unsigned int c[8], ps = 0;
        const int base = tid * 8;
#pragma unroll
        for (int i = 0; i < 8; ++i) {
            c[i] = sm.hist[0][base + i] + sm.hist[1][base + i];
            ps += c[i];
        }
        unsigned int incl = ps;
#pragma unroll
        for (int off = 1; off < 64; off <<= 1) {
            unsigned int nb = (unsigned int)__shfl_up((int)incl, off);
            if (lane >= off) incl += nb;
        }
        if (lane == 63) su4[wave] = incl;
        __syncthreads();
        unsigned int woff = 0;
        for (int w2 = 0; w2 < wave; ++w2) woff += su4[w2];
        unsigned int run = incl - ps + woff;
#pragma unroll
        for (int i = 0; i < 8; ++i) { run += c[i]; hflat[base + i] = run; }
        __syncthreads();
        if (tid < nq) {
            const float pos = qs[tid] * (float)(8192 - 1);
            const int k = (int)pos;
            const float frac = pos - (float)k;
            float v2[2];
#pragma unroll
            for (int t = 0; t < 2; ++t) {
                const unsigned int r = (unsigned int)(k + t);
                int lo_ = 0, hi_ = 2047;
                while (lo_ < hi_) {
                    const int mid = (lo_ + hi_) >> 1;
                    if (hflat[mid] > r) hi_ = mid; else lo_ = mid + 1;
                }
                const unsigned int excl = (lo_ > 0) ? hflat[lo_ - 1] : 0u;
                const unsigned int cnt  = hflat[lo_] - excl;
                const float cden = (cnt > 0u) ? (float)cnt : 1.0f;
                v2[t] = -8.0f + ((float)lo_ + ((float)(r - excl) + 0.5f) / cden) * (1.0f / COMP_SCALE);
            }
            ws[slot + tid] = v2[0] + frac * (v2[1] - v2[0]);
        }
        return;
    }

    if (blk < 518) {
        // ---------- fake fused path (4 targets/wave) ----------
        const int fb = blk - 6;
        const int b = fb >> 7, grp = fb & 127;
        const float* src = fake + (size_t)b * N_PTS * 3;
        for (int t = tid; t < N_PTS; t += 256) {
            const float* p = src + t * 3;
            sm.p.sxy[t] = make_float2(p[0], p[1]);
            sm.p.sr[t]  = fabsf(p[2]);
        }
        __syncthreads();
        const int p0 = grp * 16 + wave * 4;
        float px[4], py[4], pri[4], ovself[4], m[4][5];
#pragma unroll
        for (int t = 0; t < 4; ++t) {
            px[t] = sm.p.sxy[p0 + t].x; py[t] = sm.p.sxy[p0 + t].y;
            pri[t] = sm.p.sr[p0 + t] - 1e-4f;
            ovself[t] = fmaxf(pri[t] + sm.p.sr[p0 + t], 0.f);
            m[t][0] = m[t][1] = m[t][2] = m[t][3] = m[t][4] = INFINITY;
        }
        // pass 1: squared-dist top-5 (incl self sq=0) + feasibility overlap (guard-free)
        float acc = 0.f;
        for (int j = lane; j < N_PTS; j += 64) {
            float2 q = sm.p.sxy[j]; float br = sm.p.sr[j];
#pragma unroll
            for (int t = 0; t < 4; ++t) {
                float dx = px[t] - q.x, dy = py[t] - q.y;
                float sq = fmaf(dx, dx, dy * dy);
                ins5a(m[t], sq);
                acc += fmaxf((pri[t] + br) - RSQRT(sq), 0.f);
            }
        }
#pragma unroll
        for (int off = 1; off < 64; off <<= 1) {
#pragma unroll
            for (int t = 0; t < 4; ++t) {
                float b0 = __shfl_xor(m[t][0], off);
                float b1 = __shfl_xor(m[t][1], off);
                float b2 = __shfl_xor(m[t][2], off);
                float b3 = __shfl_xor(m[t][3], off);
                float b4 = __shfl_xor(m[t][4], off);
                float l0 = fminf(m[t][0], b4);
                float l1 = fminf(m[t][1], b3);
                float l2 = fminf(m[t][2], b2);
                float l3 = fminf(m[t][3], b1);
                float l4 = fminf(m[t][4], b0);
                CE(l0, l3); CE(l1, l4); CE(l0, l2); CE(l1, l3);
                CE(l0, l1); CE(l2, l4); CE(l1, l2); CE(l3, l4); CE(l2, l3);
                m[t][0] = l0; m[t][1] = l1; m[t][2] = l2; m[t][3] = l3; m[t][4] = l4;
            }
        }
        if (lane == 0) {
            float* kout = ws + WS_KNN_F + b * (N_PTS * 3);
#pragma unroll
            for (int t = 0; t < 4; ++t) {
                const int i = p0 + t;
                kout[i * 3 + 0] = RSQRT(m[t][0] + EPSF);
                kout[i * 3 + 1] = RSQRT(m[t][1] + EPSF);
                kout[i * 3 + 2] = RSQRT(m[t][2] + EPSF);
            }
        }
        float kth[4], invs[4], T2[4];
#pragma unroll
        for (int t = 0; t < 4; ++t) {
            kth[t] = RSQRT(m[t][4] + EPSF);
            const float sigma = fmaxf(0.1f * fmaxf(kth[t], EPSF), EPSF);
            invs[t] = 1.f / sigma;
            const float T = kth[t] + 50.f * sigma;   // arg > -50 iff dist < T
            T2[t] = T * T;
        }
        // pass 2a: lean candidate scan with wave-aggregated compaction
        unsigned int cnt[4] = {0u, 0u, 0u, 0u};
        const int lbase = wave * 4 * CAP;
        for (int it = 0; it < 32; ++it) {
            const int j = it * 64 + lane;
            float2 q = sm.p.sxy[j];
#pragma unroll
            for (int t = 0; t < 4; ++t) {
                float dx = px[t] - q.x, dy = py[t] - q.y;
                float sq = fmaf(dx, dx, dy * dy);
                const bool p = (sq <= T2[t]);
                const unsigned long long mk = __ballot(p);
                const unsigned int below = __builtin_amdgcn_mbcnt_hi(
                    (unsigned int)(mk >> 32),
                    __builtin_amdgcn_mbcnt_lo((unsigned int)mk, 0u));
                const unsigned int off = cnt[t] + below;
                if (p && off < CAP) sm.p.slist[lbase + t * CAP + off] = (unsigned short)j;
                cnt[t] += (unsigned int)__popcll((long long)mk);
            }
        }
        // pass 2b: full weighted e^{i4theta} over candidates (fallback: all pairs)
        float mypsi = 0.f;
#pragma unroll
        for (int t = 0; t < 4; ++t) {
            float swv = 0.f, srev = 0.f, simv = 0.f;
            if (cnt[t] <= CAP) {
                const int len = (int)cnt[t];
                for (int i = lane; i < len; i += 64) {
                    const int j = sm.p.slist[lbase + t * CAP + i];
                    float2 q = sm.p.sxy[j];
                    float dx = px[t] - q.x, dy = py[t] - q.y;
                    float sq = fmaf(dx, dx, dy * dy);
                    float dist = RSQRT(sq + EPSF);
                    dist = (j == p0 + t) ? INFINITY : dist;
                    float a = dx + ((fabsf(dx) < EPSF) ? EPSF : 0.f);
                    float arg = fminf(fmaxf((kth[t] - dist) * invs[t], -50.f), 50.f);
                    float e = __expf(-arg);
                    float w = __builtin_amdgcn_rcpf(1.f + e);
                    float aa = a * a, bb = dy * dy;
                    float n2 = aa + bb;
                    float z2r = aa - bb;
                    float t0 = a * dy; float z2i = t0 + t0;
                    float inv = __builtin_amdgcn_rcpf(n2);
                    float ur = z2r * inv, ui = z2i * inv;
                    float e4r = fmaf(ur, ur, -(ui * ui));
                    float t1 = ur * ui; float e4i = t1 + t1;
                    swv += w;
                    srev = fmaf(w, e4r, srev);
                    simv = fmaf(w, e4i, simv);
                }
            } else {
                for (int j = lane; j < N_PTS; j += 64) {
                    float2 q = sm.p.sxy[j];
                    float dx = px[t] - q.x, dy = py[t] - q.y;
                    float sq = fmaf(dx, dx, dy * dy);
                    float dist = RSQRT(sq + EPSF);
                    dist = (j == p0 + t) ? INFINITY : dist;
                    float a = dx + ((fabsf(dx) < EPSF) ? EPSF : 0.f);
                    float arg = fminf(fmaxf((kth[t] - dist) * invs[t], -50.f), 50.f);
                    float e = __expf(-arg);
                    float w = __builtin_amdgcn_rcpf(1.f + e);
                    float aa = a * a, bb = dy * dy;
                    float n2 = aa + bb;
                    float z2r = aa - bb;
                    float t0 = a * dy; float z2i = t0 + t0;
                    float inv = __builtin_amdgcn_rcpf(n2);
                    float ur = z2r * inv, ui = z2i * inv;
                    float e4r = fmaf(ur, ur, -(ui * ui));
                    float t1 = ur * ui; float e4i = t1 + t1;
                    swv += w;
                    srev = fmaf(w, e4r, srev);
                    simv = fmaf(w, e4i, simv);
                }
            }
#pragma unroll
            for (int off = 1; off < 64; off <<= 1) {
                swv  += __shfl_xor(swv, off);
                srev += __shfl_xor(srev, off);
                simv += __shfl_xor(simv, off);
            }
            if (lane == 0) {
                const float den = fmaxf(swv, EPSF);
                const float pr = srev / den, pi = simv / den;
                mypsi += RSQRT(fmaf(pr, pr, pi * pi));
            }
        }
        // block reductions via wave shfl + 4-float scratch (self terms removed)
        float accw = acc;
#pragma unroll
        for (int off = 1; off < 64; off <<= 1) accw += __shfl_xor(accw, off);
        if (lane == 0) s4[wave] = accw - ovself[0] - ovself[1] - ovself[2] - ovself[3];
        __syncthreads();
        if (tid == 0) ws[WS_FEAS + fb] = s4[0] + s4[1] + s4[2] + s4[3];
        __syncthreads();
        if (lane == 0) s4[wave] = mypsi;
        __syncthreads();
        if (tid == 0) ws[WS_PSIP + fb] = s4[0] + s4[1] + s4[2] + s4[3];
        if (grp == 0) {
            float rs = 0.f;
            for (int t = tid; t < N_PTS; t += 256) rs += sm.p.sr[t];
#pragma unroll
            for (int off = 1; off < 64; off <<= 1) rs += __shfl_xor(rs, off);
            __syncthreads();
            if (lane == 0) s4[wave] = rs;
            __syncthreads();
            if (tid == 0) ws[WS_RSUM + b] = s4[0] + s4[1] + s4[2] + s4[3];
        }
    } else {
        // ---------- real knn path (4 targets/wave) ----------
        const int rb = blk - 518;
        const int b = rb >> 7, grp = rb & 127;
        const float* src = real + (size_t)b * N_PTS * 3;
        for (int t = tid; t < N_PTS; t += 256) {
            const float* p = src + t * 3;
            sm.p.sxy[t] = make_float2(p[0], p[1]);
        }
        __syncthreads();
        const int p0 = grp * 16 + wave * 4;
        float px[4], py[4], m[4][3];
#pragma unroll
        for (int t = 0; t < 4; ++t) {
            px[t] = sm.p.sxy[p0 + t].x; py[t] = sm.p.sxy[p0 + t].y;
            m[t][0] = m[t][1] = m[t][2] = INFINITY;
        }
        for (int j = lane; j < N_PTS; j += 64) {
            float2 q = sm.p.sxy[j];
#pragma unroll
            for (int t = 0; t < 4; ++t) {
                float dx = px[t] - q.x, dy = py[t] - q.y;
                float sq = fmaf(dx, dx, dy * dy);
                ins3a(m[t], sq);
            }
        }
#pragma unroll
        for (int off = 1; off < 64; off <<= 1) {
#pragma unroll
            for (int t = 0; t < 4; ++t) {
                float b0 = __shfl_xor(m[t][0], off);
                float b1 = __shfl_xor(m[t][1], off);
                float b2 = __shfl_xor(m[t][2], off);
                float l0 = fminf(m[t][0], b2);
                float l1 = fminf(m[t][1], b1);
                float l2 = fminf(m[t][2], b0);
                CE(l0, l1); CE(l0, l2); CE(l1, l2);
                m[t][0] = l0; m[t][1] = l1; m[t][2] = l2;
            }
        }
        if (lane == 0) {
            float* kout = ws + WS_KNN_R + b * (N_PTS * 3);
#pragma unroll
            for (int t = 0; t < 4; ++t) {
                const int i = p0 + t;
                kout[i * 3 + 0] = RSQRT(m[t][0] + EPSF);
                kout[i * 3 + 1] = RSQRT(m[t][1] + EPSF);
                kout[i * 3 + 2] = RSQRT(m[t][2] + EPSF);
            }
        }
    }
}

// ---------------- kernel B: knn quantiles + fused final ----------------
// 8 blocks x 256 (4 waves). Block per knn array: 2048-bin LDS histogram with
// per-wave x 2-lane replicas. Last-ticket block (t==7) runs the final combine.
__global__ __launch_bounds__(256) void hs_quant_kernel(const float* __restrict__ fouts,
                                                       float* __restrict__ ws,
                                                       float* __restrict__ out) {
    __shared__ unsigned int hist[4][2048][2];   // 64 KB; flat[0..2047] reused as cum
    __shared__ unsigned int s_wsum[4];
    __shared__ float sred[256];
    __shared__ int s_last;
    unsigned int* wsu = (unsigned int*)ws;
    const int tid = threadIdx.x, wave = tid >> 6, lane = tid & 63;
    const int a = blockIdx.x;   // 0..3 real, 4..7 fake

    const float* src = ws + ((a < 4) ? WS_KNN_R + a * (N_PTS * 3)
                                     : WS_KNN_F + (a - 4) * (N_PTS * 3));
    const int n = N_PTS * 3;
    const int slot = (a < 4) ? (QDR + a * 3) : (QDF + (a - 4) * 3);

    unsigned int* hflat = &hist[0][0][0];
    for (int i = 0; i < 64; ++i) hflat[i * 256 + tid] = 0u;
    __syncthreads();

    const unsigned int rep = (unsigned int)(lane & 1);
    for (int u = 0; u < 24; ++u) {
        const float v = src[u * 256 + tid];
        const int bin = clamp_bin((int)floorf(v * KNN_SCALE));
        atomicAdd(&hist[wave][bin][rep], 1u);
    }
    __syncthreads();

    unsigned int c[8], ps = 0;
    const int base = tid * 8;
#pragma unroll
    for (int i = 0; i < 8; ++i) {
        unsigned int s = 0;
#pragma unroll
        for (int w = 0; w < 4; ++w)
            s += hist[w][base + i][0] + hist[w][base + i][1];
        c[i] = s; ps += s;
    }
    unsigned int incl = ps;
#pragma unroll
    for (int off = 1; off < 64; off <<= 1) {
        unsigned int nb = (unsigned int)__shfl_up((int)incl, off);
        if (lane >= off) incl += nb;
    }
    if (lane == 63) s_wsum[wave] = incl;
    __syncthreads();
    unsigned int woff = 0;
    for (int w2 = 0; w2 < wave; ++w2) woff += s_wsum[w2];
    unsigned int run = incl - ps + woff;
#pragma unroll
    for (int i = 0; i < 8; ++i) { run += c[i]; hflat[base + i] = run; }
    __syncthreads();

    if (tid < 3) {
        const float pos = c_qs3[tid] * (float)(n - 1);
        const int k = (int)pos;
        const float frac = pos - (float)k;
        float v2[2];
#pragma unroll
        for (int t = 0; t < 2; ++t) {
            const unsigned int r = (unsigned int)(k + t);
            int lo_ = 0, hi_ = 2047;
            while (lo_ < hi_) {
                const int mid = (lo_ + hi_) >> 1;
                if (hflat[mid] > r) hi_ = mid; else lo_ = mid + 1;
            }
            const unsigned int excl = (lo_ > 0) ? hflat[lo_ - 1] : 0u;
            const unsigned int cnt  = hflat[lo_] - excl;
            const float cden = (cnt > 0u) ? (float)cnt : 1.0f;
            v2[t] = ((float)lo_ + ((float)(r - excl) + 0.5f) / cden) * (1.0f / KNN_SCALE);
        }
        ws[slot + tid] = v2[0] + frac * (v2[1] - v2[0]);
    }

    // ---- ticket: last finisher (of 8) does the final combine ----
    __threadfence();
    __syncthreads();
    if (tid == 0) {
        const unsigned int t = atomicAdd(&wsu[WS_TICK], 1u);
        s_last = (t == 7u) ? 1 : 0;
    }
    __syncthreads();
    if (!s_last) return;
    __threadfence();

    float fs = 0.f, ps2 = 0.f;
    for (int t = tid; t < 512; t += 256) {
        fs  += ws[WS_FEAS + t];
        ps2 += ws[WS_PSIP + t];
    }
    sred[tid] = fs;
    __syncthreads();
    for (int s = 128; s > 0; s >>= 1) {
        if (tid < s) sred[tid] += sred[tid + s];
        __syncthreads();
    }
    const float s_feas = sred[0];
    __syncthreads();
    sred[tid] = ps2;
    __syncthreads();
    for (int s = 128; s > 0; s >>= 1) {
        if (tid < s) sred[tid] += sred[tid + s];
        __syncthreads();
    }
    if (tid == 0) {
        const float psi_sum = sred[0];
        const float rsum = ws[WS_RSUM + 0] + ws[WS_RSUM + 1] + ws[WS_RSUM + 2] + ws[WS_RSUM + 3];
        float loss = 0.f;
        float sacc = 0.f;
        for (int qq = 0; qq < 7; ++qq) { float d = ws[QZF + qq] - ws[QZR + qq]; sacc += d * d; }
        loss += sacc / 7.f;
        loss += (0.5f * s_feas) / ((float)N_PTS * rsum);
        float g = 0.f;
        for (int b = 0; b < B_SZ; ++b) {
            float p = fouts[b];
            g += 0.9f * fmaxf(logf(p), -100.f) + 0.1f * fmaxf(logf(1.f - p), -100.f);
        }
        loss += -g / (float)B_SZ;
        float sx = 0.f, sy = 0.f;
        for (int qq = 0; qq < 5; ++qq) {
            float dx = ws[QXF + qq] - ws[QXR + qq]; sx += dx * dx;
            float dy = ws[QYF + qq] - ws[QYR + qq]; sy += dy * dy;
        }
        loss += 0.5f * (sx / 5.f + sy / 5.f);
        float sd = 0.f;
        for (int t = 0; t < 12; ++t) { float d = ws[QDF + t] - ws[QDR + t]; sd += d * d; }
        loss += sd / 12.f;
        loss += -psi_sum / (float)(B_SZ * N_PTS);
        out[0] = loss;
    }
}

extern "C" void kernel_launch(void* const* d_in, const int* in_sizes, int n_in,
                              void* d_out, int out_size, void* d_ws, size_t ws_size,
                              hipStream_t stream) {
    (void)in_sizes; (void)n_in; (void)out_size; (void)ws_size;
    const float* real  = (const float*)d_in[0];
    const float* fake  = (const float*)d_in[1];
    const float* fouts = (const float*)d_in[2];
    float* out = (float*)d_out;
    float* ws  = (float*)d_ws;

    hipLaunchKernelGGL(hs_pair_kernel,  dim3(1030), dim3(256), 0, stream, real, fake, ws);
    hipLaunchKernelGGL(hs_quant_kernel, dim3(8),    dim3(256), 0, stream, fouts, ws, out);
}

// Round 18
// 101.760 us; speedup vs baseline: 1.0800x; 1.0800x over previous
//
#include <hip/hip_runtime.h>
#include <math.h>

#define B_SZ   4
#define N_PTS  2048
#define EPSF   1e-6f
#define CAP    500     // candidate-list capacity per (wave,target)

// ---- workspace float-index layout ----
#define WS_KNN_R 0                       // 4*6144 real knn dists
#define WS_KNN_F 24576                   // 4*6144 fake knn dists
#define WS_FEAS  49152                   // 1024 feasibility partials
#define WS_PSIP  50176                   // 1024 psi partials
#define WS_RSUM  51200                   // 4 per-batch sum|r|
#define WS_Q     51204                   // 58 quantile outputs
#define WS_TICK  51264                   // uint ticket (zeroed by pair blk 0)
#define QZF (WS_Q + 0)
#define QZR (WS_Q + 7)
#define QXF (WS_Q + 14)
#define QXR (WS_Q + 19)
#define QYF (WS_Q + 24)
#define QYR (WS_Q + 29)
#define QDR (WS_Q + 34)   // 4 batches x 3 (real knn)
#define QDF (WS_Q + 46)   // 4 batches x 3 (fake knn)
#define COMP_SCALE 128.0f     // 2048 bins over [-8,8), width 1/128
#define KNN_SCALE  512.0f     // 2048 bins over [0,4),  width 1/512

__constant__ float c_qs7[7] = {0.05f, 0.1f, 0.25f, 0.5f, 0.75f, 0.9f, 0.95f};
__constant__ float c_qs5[5] = {0.05f, 0.25f, 0.5f, 0.75f, 0.95f};
__constant__ float c_qs3[3] = {0.05f, 0.5f, 0.95f};

#define CE(a, b) { float _lo = fminf(a, b), _hi = fmaxf(a, b); a = _lo; b = _hi; }
#define RSQRT(x) __builtin_amdgcn_sqrtf(x)

__device__ __forceinline__ int clamp_bin(int b) {
    return (b < 0) ? 0 : (b > 2047 ? 2047 : b);
}

__device__ __forceinline__ void ins3a(float m[3], float v) {
    float h0 = fmaxf(m[0], v); m[0] = fminf(m[0], v);
    float h1 = fmaxf(m[1], h0); m[1] = fminf(m[1], h0);
    m[2] = fminf(m[2], h1);
}
__device__ __forceinline__ void ins5a(float m[5], float v) {
    float h0 = fmaxf(m[0], v); m[0] = fminf(m[0], v);
    float h1 = fmaxf(m[1], h0); m[1] = fminf(m[1], h0);
    float h2 = fmaxf(m[2], h1); m[2] = fminf(m[2], h1);
    float h3 = fmaxf(m[3], h2); m[3] = fminf(m[3], h2);
    m[4] = fminf(m[4], h3);
}

// kernel A shared-memory union: pair phase vs component-histogram phase
union SmemA {
    struct {
        float2 sxy[N_PTS];                 // 16 KB
        float  sr[N_PTS];                  // 8 KB
        unsigned short slist[4 * 2 * CAP]; // 8 KB
    } p;                                   // 32576 B
    unsigned int hist[4][2048];            // 32 KB (per-wave replicas; [0] reused as cum)
};

// ---------------- kernel A: pair work + component quantiles ----------------
// blocks 0..5      : component-array histogram quantiles (independent, LDS-local)
// blocks 6..1029   : fake clouds — knn + feasibility + hexatic (2 pts/wave)
// blocks 1030..1541: real clouds — knn only (4 pts/wave)
__global__ __launch_bounds__(256) void hs_pair_kernel(const float* __restrict__ real,
                                                      const float* __restrict__ fake,
                                                      float* __restrict__ ws) {
    __shared__ SmemA sm;
    __shared__ float s4[4];
    __shared__ unsigned int su4[4];
    const int tid = threadIdx.x, wave = tid >> 6, lane = tid & 63;
    const int blk = blockIdx.x;
    if (blk == 0 && tid == 0) ((unsigned int*)ws)[WS_TICK] = 0u;

    if (blk < 6) {
        // ---------- component histogram quantiles (LDS-local) ----------
        const int aid = blk;               // 0 fakeZ,1 realZ,2 fakeX,3 realX,4 fakeY,5 realY
        const float* src = ((aid & 1) ? real : fake) + ((aid < 2) ? 2 : ((aid < 4) ? 0 : 1));
        const int nq = (aid < 2) ? 7 : 5;
        const int slot = (aid < 2) ? (QZF + aid * 7) : (QXF + (aid - 2) * 5);
        const float* qs = (aid < 2) ? c_qs7 : c_qs5;

        unsigned int* hflat = &sm.hist[0][0];
        for (int i = 0; i < 32; ++i) hflat[i * 256 + tid] = 0u;
        __syncthreads();
        for (int u = 0; u < 32; ++u) {
            const float v = src[(size_t)(u * 256 + tid) * 3];
            const int bin = clamp_bin((int)floorf((v + 8.0f) * COMP_SCALE));
            atomicAdd(&sm.hist[wave][bin], 1u);
        }
        __syncthreads();
        unsigned int c[8], ps = 0;
        const int base = tid * 8;
#pragma unroll
        for (int i = 0; i < 8; ++i) {
            c[i] = sm.hist[0][base + i] + sm.hist[1][base + i]
                 + sm.hist[2][base + i] + sm.hist[3][base + i];
            ps += c[i];
        }
        unsigned int incl = ps;
#pragma unroll
        for (int off = 1; off < 64; off <<= 1) {
            unsigned int nb = (unsigned int)__shfl_up((int)incl, off);
            if (lane >= off) incl += nb;
        }
        if (lane == 63) su4[wave] = incl;
        __syncthreads();
        unsigned int woff = 0;
        for (int w2 = 0; w2 < wave; ++w2) woff += su4[w2];
        unsigned int run = incl - ps + woff;
#pragma unroll
        for (int i = 0; i < 8; ++i) { run += c[i]; hflat[base + i] = run; }
        __syncthreads();
        if (tid < nq) {
            const float pos = qs[tid] * (float)(8192 - 1);
            const int k = (int)pos;
            const float frac = pos - (float)k;
            float v2[2];
#pragma unroll
            for (int t = 0; t < 2; ++t) {
                const unsigned int r = (unsigned int)(k + t);
                int lo_ = 0, hi_ = 2047;
                while (lo_ < hi_) {
                    const int mid = (lo_ + hi_) >> 1;
                    if (hflat[mid] > r) hi_ = mid; else lo_ = mid + 1;
                }
                const unsigned int excl = (lo_ > 0) ? hflat[lo_ - 1] : 0u;
                const unsigned int cnt  = hflat[lo_] - excl;
                const float cden = (cnt > 0u) ? (float)cnt : 1.0f;
                v2[t] = -8.0f + ((float)lo_ + ((float)(r - excl) + 0.5f) / cden) * (1.0f / COMP_SCALE);
            }
            ws[slot + tid] = v2[0] + frac * (v2[1] - v2[0]);
        }
        return;
    }

    if (blk < 1030) {
        // ---------- fake fused path (2 targets/wave) ----------
        const int fb = blk - 6;
        const int b = fb >> 8, grp = fb & 255;
        const float* src = fake + (size_t)b * N_PTS * 3;
        for (int t = tid; t < N_PTS; t += 256) {
            const float* p = src + t * 3;
            sm.p.sxy[t] = make_float2(p[0], p[1]);
            sm.p.sr[t]  = fabsf(p[2]);
        }
        __syncthreads();
        const int p0 = grp * 8 + wave * 2;
        float px[2], py[2], pri[2], ovself[2], m[2][5];
#pragma unroll
        for (int t = 0; t < 2; ++t) {
            px[t] = sm.p.sxy[p0 + t].x; py[t] = sm.p.sxy[p0 + t].y;
            pri[t] = sm.p.sr[p0 + t] - 1e-4f;
            ovself[t] = fmaxf(pri[t] + sm.p.sr[p0 + t], 0.f);
            m[t][0] = m[t][1] = m[t][2] = m[t][3] = m[t][4] = INFINITY;
        }
        // pass 1: squared-dist top-5 (incl self sq=0) + feasibility overlap (guard-free)
        float acc = 0.f;
        for (int j = lane; j < N_PTS; j += 64) {
            float2 q = sm.p.sxy[j]; float br = sm.p.sr[j];
#pragma unroll
            for (int t = 0; t < 2; ++t) {
                float dx = px[t] - q.x, dy = py[t] - q.y;
                float sq = fmaf(dx, dx, dy * dy);
                ins5a(m[t], sq);
                acc += fmaxf((pri[t] + br) - RSQRT(sq), 0.f);
            }
        }
#pragma unroll
        for (int off = 1; off < 64; off <<= 1) {
#pragma unroll
            for (int t = 0; t < 2; ++t) {
                float b0 = __shfl_xor(m[t][0], off);
                float b1 = __shfl_xor(m[t][1], off);
                float b2 = __shfl_xor(m[t][2], off);
                float b3 = __shfl_xor(m[t][3], off);
                float b4 = __shfl_xor(m[t][4], off);
                float l0 = fminf(m[t][0], b4);
                float l1 = fminf(m[t][1], b3);
                float l2 = fminf(m[t][2], b2);
                float l3 = fminf(m[t][3], b1);
                float l4 = fminf(m[t][4], b0);
                CE(l0, l3); CE(l1, l4); CE(l0, l2); CE(l1, l3);
                CE(l0, l1); CE(l2, l4); CE(l1, l2); CE(l3, l4); CE(l2, l3);
                m[t][0] = l0; m[t][1] = l1; m[t][2] = l2; m[t][3] = l3; m[t][4] = l4;
            }
        }
        if (lane == 0) {
            float* kout = ws + WS_KNN_F + b * (N_PTS * 3);
#pragma unroll
            for (int t = 0; t < 2; ++t) {
                const int i = p0 + t;
                kout[i * 3 + 0] = RSQRT(m[t][0] + EPSF);
                kout[i * 3 + 1] = RSQRT(m[t][1] + EPSF);
                kout[i * 3 + 2] = RSQRT(m[t][2] + EPSF);
            }
        }
        float kth[2], invs[2], T2[2];
#pragma unroll
        for (int t = 0; t < 2; ++t) {
            kth[t] = RSQRT(m[t][4] + EPSF);
            const float sigma = fmaxf(0.1f * fmaxf(kth[t], EPSF), EPSF);
            invs[t] = 1.f / sigma;
            const float T = kth[t] + 50.f * sigma;   // arg > -50 iff dist < T
            T2[t] = T * T;
        }
        // pass 2a: lean candidate scan with wave-aggregated compaction
        unsigned int cnt[2] = {0u, 0u};
        const int lbase = wave * 2 * CAP;
        for (int it = 0; it < 32; ++it) {
            const int j = it * 64 + lane;
            float2 q = sm.p.sxy[j];
#pragma unroll
            for (int t = 0; t < 2; ++t) {
                float dx = px[t] - q.x, dy = py[t] - q.y;
                float sq = fmaf(dx, dx, dy * dy);
                const bool p = (sq <= T2[t]);
                const unsigned long long mk = __ballot(p);
                const unsigned int below = __builtin_amdgcn_mbcnt_hi(
                    (unsigned int)(mk >> 32),
                    __builtin_amdgcn_mbcnt_lo((unsigned int)mk, 0u));
                const unsigned int off = cnt[t] + below;
                if (p && off < CAP) sm.p.slist[lbase + t * CAP + off] = (unsigned short)j;
                cnt[t] += (unsigned int)__popcll((long long)mk);
            }
        }
        // pass 2b: full weighted e^{i4theta} over candidates (fallback: all pairs)
        float mypsi = 0.f;
#pragma unroll
        for (int t = 0; t < 2; ++t) {
            float swv = 0.f, srev = 0.f, simv = 0.f;
            if (cnt[t] <= CAP) {
                const int len = (int)cnt[t];
                for (int i = lane; i < len; i += 64) {
                    const int j = sm.p.slist[lbase + t * CAP + i];
                    float2 q = sm.p.sxy[j];
                    float dx = px[t] - q.x, dy = py[t] - q.y;
                    float sq = fmaf(dx, dx, dy * dy);
                    float dist = RSQRT(sq + EPSF);
                    dist = (j == p0 + t) ? INFINITY : dist;
                    float a = dx + ((fabsf(dx) < EPSF) ? EPSF : 0.f);
                    float arg = fminf(fmaxf((kth[t] - dist) * invs[t], -50.f), 50.f);
                    float e = __expf(-arg);
                    float w = __builtin_amdgcn_rcpf(1.f + e);
                    float aa = a * a, bb = dy * dy;
                    float n2 = aa + bb;
                    float z2r = aa - bb;
                    float t0 = a * dy; float z2i = t0 + t0;
                    float inv = __builtin_amdgcn_rcpf(n2);
                    float ur = z2r * inv, ui = z2i * inv;
                    float e4r = fmaf(ur, ur, -(ui * ui));
                    float t1 = ur * ui; float e4i = t1 + t1;
                    swv += w;
                    srev = fmaf(w, e4r, srev);
                    simv = fmaf(w, e4i, simv);
                }
            } else {
                for (int j = lane; j < N_PTS; j += 64) {
                    float2 q = sm.p.sxy[j];
                    float dx = px[t] - q.x, dy = py[t] - q.y;
                    float sq = fmaf(dx, dx, dy * dy);
                    float dist = RSQRT(sq + EPSF);
                    dist = (j == p0 + t) ? INFINITY : dist;
                    float a = dx + ((fabsf(dx) < EPSF) ? EPSF : 0.f);
                    float arg = fminf(fmaxf((kth[t] - dist) * invs[t], -50.f), 50.f);
                    float e = __expf(-arg);
                    float w = __builtin_amdgcn_rcpf(1.f + e);
                    float aa = a * a, bb = dy * dy;
                    float n2 = aa + bb;
                    float z2r = aa - bb;
                    float t0 = a * dy; float z2i = t0 + t0;
                    float inv = __builtin_amdgcn_rcpf(n2);
                    float ur = z2r * inv, ui = z2i * inv;
                    float e4r = fmaf(ur, ur, -(ui * ui));
                    float t1 = ur * ui; float e4i = t1 + t1;
                    swv += w;
                    srev = fmaf(w, e4r, srev);
                    simv = fmaf(w, e4i, simv);
                }
            }
#pragma unroll
            for (int off = 1; off < 64; off <<= 1) {
                swv  += __shfl_xor(swv, off);
                srev += __shfl_xor(srev, off);
                simv += __shfl_xor(simv, off);
            }
            if (lane == 0) {
                const float den = fmaxf(swv, EPSF);
                const float pr = srev / den, pi = simv / den;
                mypsi += RSQRT(fmaf(pr, pr, pi * pi));
            }
        }
        // block reductions via wave shfl + 4-float scratch (self terms removed)
        float accw = acc;
#pragma unroll
        for (int off = 1; off < 64; off <<= 1) accw += __shfl_xor(accw, off);
        if (lane == 0) s4[wave] = accw - ovself[0] - ovself[1];
        __syncthreads();
        if (tid == 0) ws[WS_FEAS + fb] = s4[0] + s4[1] + s4[2] + s4[3];
        __syncthreads();
        if (lane == 0) s4[wave] = mypsi;
        __syncthreads();
        if (tid == 0) ws[WS_PSIP + fb] = s4[0] + s4[1] + s4[2] + s4[3];
        if (grp == 0) {
            float rs = 0.f;
            for (int t = tid; t < N_PTS; t += 256) rs += sm.p.sr[t];
#pragma unroll
            for (int off = 1; off < 64; off <<= 1) rs += __shfl_xor(rs, off);
            __syncthreads();
            if (lane == 0) s4[wave] = rs;
            __syncthreads();
            if (tid == 0) ws[WS_RSUM + b] = s4[0] + s4[1] + s4[2] + s4[3];
        }
    } else {
        // ---------- real knn path (4 targets/wave) ----------
        const int rb = blk - 1030;
        const int b = rb >> 7, grp = rb & 127;
        const float* src = real + (size_t)b * N_PTS * 3;
        for (int t = tid; t < N_PTS; t += 256) {
            const float* p = src + t * 3;
            sm.p.sxy[t] = make_float2(p[0], p[1]);
        }
        __syncthreads();
        const int p0 = grp * 16 + wave * 4;
        float px[4], py[4], m[4][3];
#pragma unroll
        for (int t = 0; t < 4; ++t) {
            px[t] = sm.p.sxy[p0 + t].x; py[t] = sm.p.sxy[p0 + t].y;
            m[t][0] = m[t][1] = m[t][2] = INFINITY;
        }
        for (int j = lane; j < N_PTS; j += 64) {
            float2 q = sm.p.sxy[j];
#pragma unroll
            for (int t = 0; t < 4; ++t) {
                float dx = px[t] - q.x, dy = py[t] - q.y;
                float sq = fmaf(dx, dx, dy * dy);
                ins3a(m[t], sq);
            }
        }
#pragma unroll
        for (int off = 1; off < 64; off <<= 1) {
#pragma unroll
            for (int t = 0; t < 4; ++t) {
                float b0 = __shfl_xor(m[t][0], off);
                float b1 = __shfl_xor(m[t][1], off);
                float b2 = __shfl_xor(m[t][2], off);
                float l0 = fminf(m[t][0], b2);
                float l1 = fminf(m[t][1], b1);
                float l2 = fminf(m[t][2], b0);
                CE(l0, l1); CE(l0, l2); CE(l1, l2);
                m[t][0] = l0; m[t][1] = l1; m[t][2] = l2;
            }
        }
        if (lane == 0) {
            float* kout = ws + WS_KNN_R + b * (N_PTS * 3);
#pragma unroll
            for (int t = 0; t < 4; ++t) {
                const int i = p0 + t;
                kout[i * 3 + 0] = RSQRT(m[t][0] + EPSF);
                kout[i * 3 + 1] = RSQRT(m[t][1] + EPSF);
                kout[i * 3 + 2] = RSQRT(m[t][2] + EPSF);
            }
        }
    }
}

// ---------------- kernel B: knn quantiles + fused final ----------------
// 8 blocks x 256 (4 waves). Block per knn array: 2048-bin LDS histogram with
// per-wave x 2-lane replicas. Last-ticket block (t==7) runs the final combine.
__global__ __launch_bounds__(256) void hs_quant_kernel(const float* __restrict__ fouts,
                                                       float* __restrict__ ws,
                                                       float* __restrict__ out) {
    __shared__ unsigned int hist[4][2048][2];   // 64 KB; flat[0..2047] reused as cum
    __shared__ unsigned int s_wsum[4];
    __shared__ float sred[256];
    __shared__ int s_last;
    unsigned int* wsu = (unsigned int*)ws;
    const int tid = threadIdx.x, wave = tid >> 6, lane = tid & 63;
    const int a = blockIdx.x;   // 0..3 real, 4..7 fake

    const float* src = ws + ((a < 4) ? WS_KNN_R + a * (N_PTS * 3)
                                     : WS_KNN_F + (a - 4) * (N_PTS * 3));
    const int n = N_PTS * 3;
    const int slot = (a < 4) ? (QDR + a * 3) : (QDF + (a - 4) * 3);

    unsigned int* hflat = &hist[0][0][0];
    for (int i = 0; i < 64; ++i) hflat[i * 256 + tid] = 0u;
    __syncthreads();

    const unsigned int rep = (unsigned int)(lane & 1);
    for (int u = 0; u < 24; ++u) {
        const float v = src[u * 256 + tid];
        const int bin = clamp_bin((int)floorf(v * KNN_SCALE));
        atomicAdd(&hist[wave][bin][rep], 1u);
    }
    __syncthreads();

    unsigned int c[8], ps = 0;
    const int base = tid * 8;
#pragma unroll
    for (int i = 0; i < 8; ++i) {
        unsigned int s = 0;
#pragma unroll
        for (int w = 0; w < 4; ++w)
            s += hist[w][base + i][0] + hist[w][base + i][1];
        c[i] = s; ps += s;
    }
    unsigned int incl = ps;
#pragma unroll
    for (int off = 1; off < 64; off <<= 1) {
        unsigned int nb = (unsigned int)__shfl_up((int)incl, off);
        if (lane >= off) incl += nb;
    }
    if (lane == 63) s_wsum[wave] = incl;
    __syncthreads();
    unsigned int woff = 0;
    for (int w2 = 0; w2 < wave; ++w2) woff += s_wsum[w2];
    unsigned int run = incl - ps + woff;
#pragma unroll
    for (int i = 0; i < 8; ++i) { run += c[i]; hflat[base + i] = run; }
    __syncthreads();

    if (tid < 3) {
        const float pos = c_qs3[tid] * (float)(n - 1);
        const int k = (int)pos;
        const float frac = pos - (float)k;
        float v2[2];
#pragma unroll
        for (int t = 0; t < 2; ++t) {
            const unsigned int r = (unsigned int)(k + t);
            int lo_ = 0, hi_ = 2047;
            while (lo_ < hi_) {
                const int mid = (lo_ + hi_) >> 1;
                if (hflat[mid] > r) hi_ = mid; else lo_ = mid + 1;
            }
            const unsigned int excl = (lo_ > 0) ? hflat[lo_ - 1] : 0u;
            const unsigned int cnt  = hflat[lo_] - excl;
            const float cden = (cnt > 0u) ? (float)cnt : 1.0f;
            v2[t] = ((float)lo_ + ((float)(r - excl) + 0.5f) / cden) * (1.0f / KNN_SCALE);
        }
        ws[slot + tid] = v2[0] + frac * (v2[1] - v2[0]);
    }

    // ---- ticket: last finisher (of 8) does the final combine ----
    __threadfence();
    __syncthreads();
    if (tid == 0) {
        const unsigned int t = atomicAdd(&wsu[WS_TICK], 1u);
        s_last = (t == 7u) ? 1 : 0;
    }
    __syncthreads();
    if (!s_last) return;
    __threadfence();

    float fs = 0.f, ps2 = 0.f;
    for (int t = tid; t < 1024; t += 256) {
        fs  += ws[WS_FEAS + t];
        ps2 += ws[WS_PSIP + t];
    }
    sred[tid] = fs;
    __syncthreads();
    for (int s = 128; s > 0; s >>= 1) {
        if (tid < s) sred[tid] += sred[tid + s];
        __syncthreads();
    }
    const float s_feas = sred[0];
    __syncthreads();
    sred[tid] = ps2;
    __syncthreads();
    for (int s = 128; s > 0; s >>= 1) {
        if (tid < s) sred[tid] += sred[tid + s];
        __syncthreads();
    }
    if (tid == 0) {
        const float psi_sum = sred[0];
        const float rsum = ws[WS_RSUM + 0] + ws[WS_RSUM + 1] + ws[WS_RSUM + 2] + ws[WS_RSUM + 3];
        float loss = 0.f;
        float sacc = 0.f;
        for (int qq = 0; qq < 7; ++qq) { float d = ws[QZF + qq] - ws[QZR + qq]; sacc += d * d; }
        loss += sacc / 7.f;
        loss += (0.5f * s_feas) / ((float)N_PTS * rsum);
        float g = 0.f;
        for (int b = 0; b < B_SZ; ++b) {
            float p = fouts[b];
            g += 0.9f * fmaxf(logf(p), -100.f) + 0.1f * fmaxf(logf(1.f - p), -100.f);
        }
        loss += -g / (float)B_SZ;
        float sx = 0.f, sy = 0.f;
        for (int qq = 0; qq < 5; ++qq) {
            float dx = ws[QXF + qq] - ws[QXR + qq]; sx += dx * dx;
            float dy = ws[QYF + qq] - ws[QYR + qq]; sy += dy * dy;
        }
        loss += 0.5f * (sx / 5.f + sy / 5.f);
        float sd = 0.f;
        for (int t = 0; t < 12; ++t) { float d = ws[QDF + t] - ws[QDR + t]; sd += d * d; }
        loss += sd / 12.f;
        loss += -psi_sum / (float)(B_SZ * N_PTS);
        out[0] = loss;
    }
}

extern "C" void kernel_launch(void* const* d_in, const int* in_sizes, int n_in,
                              void* d_out, int out_size, void* d_ws, size_t ws_size,
                              hipStream_t stream) {
    (void)in_sizes; (void)n_in; (void)out_size; (void)ws_size;
    const float* real  = (const float*)d_in[0];
    const float* fake  = (const float*)d_in[1];
    const float* fouts = (const float*)d_in[2];
    float* out = (float*)d_out;
    float* ws  = (float*)d_ws;

    hipLaunchKernelGGL(hs_pair_kernel,  dim3(1542), dim3(256), 0, stream, real, fake, ws);
    hipLaunchKernelGGL(hs_quant_kernel, dim3(8),    dim3(256), 0, stream, fouts, ws, out);
}